// Round 7
// baseline (48.341 us; speedup 1.0000x reference)
//
#include <hip/hip_runtime.h>

// CrossNetwork flattened (R7): out = x*scale + (b0+b1+b2), where
//   d_i = x.W_i ; c01 = b0.W1 ; c02 = (b0+b1).W2   (c01,c02 row-independent)
//   s0=d0; s1=(1+s0)d1+c01; s2=(1+s0+s1)d2+c02; scale=1+s0+s1+s2
// R7: ROWS=4 rows per 512-thread block (thread owns ONE float4 column per
// row -> x=16 VGPR, total ~48, under the 64 cliff R4 hit). W/b L2 re-read
// traffic drops 393 MB -> 196 MB (R6 confirmed this stream is the limiter:
// halving it 786->393 MB gained 4.4 us).

constexpr int D_DIM    = 2048;
constexpr int NTHREADS = 512;   // = D_DIM/4 float4 columns
constexpr int ROWS     = 4;
constexpr int NWAVES   = NTHREADS / 64;

__device__ __forceinline__ float dot4(const float4 a, const float4 b) {
    return a.x*b.x + a.y*b.y + a.z*b.z + a.w*b.w;
}

__global__ __launch_bounds__(NTHREADS)
void cross_network_kernel(const float* __restrict__ x,
                          const float* __restrict__ W,
                          const float* __restrict__ bias,
                          float* __restrict__ out) {
    const int row0 = blockIdx.x * ROWS;
    const int t    = threadIdx.x;          // float4 column index, 0..511
    const int lane = t & 63;
    const int wave = t >> 6;

    // x rows in registers: 4 rows x 1 float4 = 16 VGPR.
    float4 xv[ROWS];
#pragma unroll
    for (int r = 0; r < ROWS; ++r)
        xv[r] = reinterpret_cast<const float4*>(x + (size_t)(row0 + r) * D_DIM)[t];

    const float4* w0r = reinterpret_cast<const float4*>(W);
    const float4* w1r = reinterpret_cast<const float4*>(W + D_DIM);
    const float4* w2r = reinterpret_cast<const float4*>(W + 2 * D_DIM);
    const float4* b0r = reinterpret_cast<const float4*>(bias);
    const float4* b1r = reinterpret_cast<const float4*>(bias + D_DIM);
    const float4* b2r = reinterpret_cast<const float4*>(bias + 2 * D_DIM);

    // 14 partials: p[i][r] = x_r . W_i (per-thread slice), q1 = b0.W1,
    // q2 = (b0+b1).W2. bs = running bias sum (4 VGPR).
    float p[3][ROWS], q1, q2;
    float4 bs;
    {
        const float4 w = w0r[t];
#pragma unroll
        for (int r = 0; r < ROWS; ++r) p[0][r] = dot4(xv[r], w);
    }
    {
        const float4 w = w1r[t];
#pragma unroll
        for (int r = 0; r < ROWS; ++r) p[1][r] = dot4(xv[r], w);
        bs = b0r[t];
        q1 = dot4(bs, w);
    }
    {
        const float4 w = w2r[t];
#pragma unroll
        for (int r = 0; r < ROWS; ++r) p[2][r] = dot4(xv[r], w);
        const float4 b1v = b1r[t];
        bs.x += b1v.x; bs.y += b1v.y; bs.z += b1v.z; bs.w += b1v.w;
        q2 = dot4(bs, w);
    }

    // One reduction round for all 14 partials: wave butterfly + LDS combine.
#pragma unroll
    for (int off = 32; off >= 1; off >>= 1) {
#pragma unroll
        for (int i = 0; i < 3; ++i)
#pragma unroll
            for (int r = 0; r < ROWS; ++r)
                p[i][r] += __shfl_down(p[i][r], off, 64);
        q1 += __shfl_down(q1, off, 64);
        q2 += __shfl_down(q2, off, 64);
    }

    __shared__ float sred[14][NWAVES];
    if (lane == 0) {
#pragma unroll
        for (int i = 0; i < 3; ++i)
#pragma unroll
            for (int r = 0; r < ROWS; ++r)
                sred[i * ROWS + r][wave] = p[i][r];
        sred[12][wave] = q1;
        sred[13][wave] = q2;
    }
    __syncthreads();

    float d[14];
#pragma unroll
    for (int k = 0; k < 14; ++k) {
        float s = 0.0f;
#pragma unroll
        for (int w = 0; w < NWAVES; ++w) s += sred[k][w];
        d[k] = s;
    }
    const float c01 = d[12], c02 = d[13];

    float scale[ROWS];
#pragma unroll
    for (int r = 0; r < ROWS; ++r) {
        const float s0 = d[0 * ROWS + r];
        const float t1 = 1.0f + s0;
        const float s1 = fmaf(t1, d[1 * ROWS + r], c01);
        const float t2 = t1 + s1;
        const float s2 = fmaf(t2, d[2 * ROWS + r], c02);
        scale[r] = t2 + s2;
    }

    // bsum = (b0+b1) + b2 ; out_r = x_r * scale_r + bsum
    {
        const float4 b2v = b2r[t];
        bs.x += b2v.x; bs.y += b2v.y; bs.z += b2v.z; bs.w += b2v.w;
    }

#pragma unroll
    for (int r = 0; r < ROWS; ++r) {
        float4 v;
        v.x = fmaf(xv[r].x, scale[r], bs.x);
        v.y = fmaf(xv[r].y, scale[r], bs.y);
        v.z = fmaf(xv[r].z, scale[r], bs.z);
        v.w = fmaf(xv[r].w, scale[r], bs.w);
        reinterpret_cast<float4*>(out + (size_t)(row0 + r) * D_DIM)[t] = v;
    }
}

extern "C" void kernel_launch(void* const* d_in, const int* in_sizes, int n_in,
                              void* d_out, int out_size, void* d_ws, size_t ws_size,
                              hipStream_t stream) {
    const float* x    = (const float*)d_in[0];
    const float* W    = (const float*)d_in[1];
    const float* bias = (const float*)d_in[2];
    float* out = (float*)d_out;

    const int B = in_sizes[0] / D_DIM;      // 16384
    cross_network_kernel<<<B / ROWS, NTHREADS, 0, stream>>>(x, W, bias, out);
}